// Round 11
// baseline (204.401 us; speedup 1.0000x reference)
//
#include <hip/hip_runtime.h>
#include <stdint.h>

// B=2, S=2048, D=1024, H=16, HD=64. fp32 in/out, bf16 MFMA internally.

typedef __attribute__((ext_vector_type(8))) short short8;
typedef __attribute__((ext_vector_type(4))) float floatx4;

#define S_LEN 2048
#define D_DIM 1024
#define NH 16
#define HD 64
#define L2E 1.44269504088896340736f

__device__ __forceinline__ short f2bf(float f) {
    uint32_t u = __builtin_bit_cast(uint32_t, f);
    uint32_t r = u + 0x7fffu + ((u >> 16) & 1u);   // RNE
    return (short)(r >> 16);
}
__device__ __forceinline__ uint32_t pack2(float a, float b) {
#if __has_builtin(__builtin_amdgcn_cvt_pk_bf16_f32)
    auto v = __builtin_amdgcn_cvt_pk_bf16_f32(a, b);
    uint32_t r; __builtin_memcpy(&r, &v, sizeof(r)); return r;
#else
    return (uint32_t)(uint16_t)f2bf(a) | ((uint32_t)(uint16_t)f2bf(b) << 16);
#endif
}
__device__ __forceinline__ void gll16(const void* g, void* l) {
    __builtin_amdgcn_global_load_lds(
        (const __attribute__((address_space(1))) void*)g,
        (__attribute__((address_space(3))) void*)l, 16, 0, 0);
}

// ---------------- prep: cast X + transpose-cast 4 weights, one launch ----------------
__global__ __launch_bounds__(256) void prep_kernel(const float* __restrict__ X,
                                                   const float* __restrict__ Wq,
                                                   const float* __restrict__ Wk,
                                                   const float* __restrict__ Wv,
                                                   const float* __restrict__ Wo,
                                                   short* __restrict__ Xb,
                                                   short* __restrict__ WqkvT,
                                                   short* __restrict__ WoT) {
    __shared__ float tile[32][33];
    const int id = blockIdx.x, tid = threadIdx.x;
    if (id < 4096) {                                  // castx: one float4/thread
        const int i = id * 256 + tid;
        const float4 v = *(const float4*)(X + (size_t)i * 4);
        uint2 o;
        o.x = pack2(v.x, v.y);
        o.y = pack2(v.z, v.w);
        *(uint2*)(Xb + (size_t)i * 4) = o;
    } else {                                          // tcast: 32x32 tile
        const int f = id - 4096;                      // 0..4095
        const int z = f >> 10, r = f & 1023;
        const float* W = (z == 0) ? Wq : (z == 1) ? Wk : (z == 2) ? Wv : Wo;
        short* WT = (z < 3) ? (WqkvT + (size_t)z * 1024 * 1024) : WoT;
        const int bx = (r & 31) * 32, by = (r >> 5) * 32;
        const int tx = tid & 31, ty = tid >> 5;       // 32 x 8
        for (int i = 0; i < 32; i += 8)
            tile[ty + i][tx] = W[(size_t)(bx + ty + i) * D_DIM + by + tx];
        __syncthreads();
        for (int i = 0; i < 32; i += 8)
            WT[(size_t)(by + ty + i) * D_DIM + bx + tx] = f2bf(tile[tx][ty + i]);
    }
}

// ---------------- GEMM mainloop: 128x128 tile, BK=64, 8 waves ----------------
__device__ __forceinline__ void gemm_main8(const short* __restrict__ A,
                                           const short* __restrict__ BT,
                                           short* As, short* Bs,
                                           int m0, int n0, floatx4 (&acc)[4][2],
                                           int tid) {
    const int lane = tid & 63, ln = lane & 15, quad = lane >> 4;
    const int wave = tid >> 6;
    const int mw = (wave & 1) * 64, nw = (wave >> 1) * 32;
    for (int k0 = 0; k0 < D_DIM; k0 += 64) {
        __syncthreads();
        for (int t = 0; t < 2; t++) {
            const int c = t * 512 + tid;             // 0..1023
            const int row = c >> 3, pos = c & 7, src = pos ^ (row & 7);
            gll16(A  + (size_t)(m0 + row) * D_DIM + k0 + src * 8, As + c * 8);
            gll16(BT + (size_t)(n0 + row) * D_DIM + k0 + src * 8, Bs + c * 8);
        }
        __syncthreads();
        for (int ks = 0; ks < 2; ks++) {
            short8 a[4], b[2];
            for (int i = 0; i < 4; i++) {
                const int row = mw + i * 16 + ln;
                a[i] = *(const short8*)(As + row * 64 + (((ks * 4 + quad) ^ (ln & 7)) * 8));
            }
            for (int j = 0; j < 2; j++) {
                const int row = nw + j * 16 + ln;
                b[j] = *(const short8*)(Bs + row * 64 + (((ks * 4 + quad) ^ (ln & 7)) * 8));
            }
            for (int i = 0; i < 4; i++)
                for (int j = 0; j < 2; j++)
                    acc[i][j] = __builtin_amdgcn_mfma_f32_16x16x32_bf16(a[i], b[j], acc[i][j], 0, 0, 0);
        }
    }
}

// fused QKV: grid (32, 24), 512 threads. Q pre-scaled by log2(e).
__global__ __launch_bounds__(512) void gemm_qkv_kernel(const short* __restrict__ Xb,
                                                       const short* __restrict__ WT,
                                                       short* __restrict__ Qb,
                                                       short* __restrict__ Kb,
                                                       short* __restrict__ Vtb) {
    __shared__ __align__(16) short As[128 * 64];
    __shared__ __align__(16) short Bs[128 * 64];
    const int m0 = blockIdx.x * 128, n0 = blockIdx.y * 128;
    floatx4 acc[4][2] = {};
    gemm_main8(Xb, WT, As, Bs, m0, n0, acc, threadIdx.x);

    const int tid = threadIdx.x, wave = tid >> 6, lane = tid & 63;
    const int ln = lane & 15, quad = lane >> 4;
    const int mw = (wave & 1) * 64, nw = (wave >> 1) * 32;
    const int nsel = n0 >> 10;              // 0:Q 1:K 2:V
    const float qs = (nsel == 0) ? L2E : 1.f;
    short* outB = (nsel == 0) ? Qb : (nsel == 1 ? Kb : Vtb);
    for (int i = 0; i < 4; i++)
        for (int j = 0; j < 2; j++)
            for (int r = 0; r < 4; r++) {
                const int row = m0 + mw + i * 16 + quad * 4 + r;   // token
                const int col = (n0 & 1023) + nw + j * 16 + ln;    // feature
                const int bb = row >> 11, s = row & (S_LEN - 1);
                const int h = col >> 6, hd = col & (HD - 1);
                const short v = f2bf(acc[i][j][r] * qs);
                if (nsel < 2)
                    outB[(((size_t)(bb * NH + h)) * S_LEN + s) * HD + hd] = v;
                else
                    outB[(((size_t)(bb * NH + h)) * HD + hd) * S_LEN + s] = v;
            }
}

// ---------------- output projection: BM=128 x BN=64, grid (32,16) ----------------
__global__ __launch_bounds__(512) void gemm_out_kernel(const short* __restrict__ Cb,
                                                       const short* __restrict__ WoT,
                                                       float* __restrict__ out,
                                                       const float* __restrict__ bias) {
    __shared__ __align__(16) short As[128 * 64];   // 16 KB
    __shared__ __align__(16) short Bs[64 * 64];    // 8 KB
    const int m0 = blockIdx.x * 128, n0 = blockIdx.y * 64;
    const int tid = threadIdx.x, lane = tid & 63;
    const int ln = lane & 15, quad = lane >> 4;
    const int wave = tid >> 6;
    const int mw = (wave & 3) * 32, nw = (wave >> 2) * 32;

    floatx4 acc[2][2] = {};

    for (int k0 = 0; k0 < D_DIM; k0 += 64) {
        __syncthreads();
        for (int t = 0; t < 2; t++) {            // A: 1024 chunks
            const int c = t * 512 + tid;
            const int row = c >> 3, pos = c & 7, src = pos ^ (row & 7);
            gll16(Cb + (size_t)(m0 + row) * D_DIM + k0 + src * 8, As + c * 8);
        }
        {                                        // B: 512 chunks
            const int c = tid;
            const int row = c >> 3, pos = c & 7, src = pos ^ (row & 7);
            gll16(WoT + (size_t)(n0 + row) * D_DIM + k0 + src * 8, Bs + c * 8);
        }
        __syncthreads();
        for (int ks = 0; ks < 2; ks++) {
            short8 a[2], b[2];
            for (int i = 0; i < 2; i++) {
                const int row = mw + i * 16 + ln;
                a[i] = *(const short8*)(As + row * 64 + (((ks * 4 + quad) ^ (ln & 7)) * 8));
            }
            for (int j = 0; j < 2; j++) {
                const int row = nw + j * 16 + ln;
                b[j] = *(const short8*)(Bs + row * 64 + (((ks * 4 + quad) ^ (ln & 7)) * 8));
            }
            for (int i = 0; i < 2; i++)
                for (int j = 0; j < 2; j++)
                    acc[i][j] = __builtin_amdgcn_mfma_f32_16x16x32_bf16(a[i], b[j], acc[i][j], 0, 0, 0);
        }
    }

    for (int i = 0; i < 2; i++)
        for (int j = 0; j < 2; j++)
            for (int r = 0; r < 4; r++) {
                const int row = m0 + mw + i * 16 + quad * 4 + r;
                const int col = n0 + nw + j * 16 + ln;
                out[(size_t)row * D_DIM + col] = acc[i][j][r] + bias[col];
            }
}

// ---------------- causal flash attention: 128 queries/block, 64-key tiles ----------------
// Wave owns 32 queries (2 subtiles of 16); each K/V fragment read feeds 2x the
// MFMAs (LDS-pipe was the bottleneck). Fixed-base softmax (Q pre-scaled by
// log2e). 736 blocks: qt'>=9 split into 2 key chunks (fp32 partials, 14.7 MB,
// dead ws region); XCD head affinity; longest task first.
#define PST2 72

__global__ __launch_bounds__(256) void attn_kernel(const short* __restrict__ Q,
                                                   const short* __restrict__ Kg,
                                                   const short* __restrict__ Vt,
                                                   short* __restrict__ ctx,
                                                   float* __restrict__ Opart,
                                                   float* __restrict__ Lpart) {
    __shared__ __align__(16) short Ks[64 * 64];            // [key][hd]     8 KB
    __shared__ __align__(16) short Vs[64 * 64];            // [hd][key]     8 KB
    __shared__ __align__(16) short Ps[4][2 * 16 * PST2];   // per-wave, per-qs

    const int tid = threadIdx.x, wave = tid >> 6, lane = tid & 63;
    const int ln = lane & 15, quad = lane >> 4;

    const int id = blockIdx.x;            // 0..735
    const int bh = (id & 7) + 8 * ((id >> 3) & 3);
    const int t = id >> 5;                // 0..22
    int qt, k_begin, k_end, pidx;         // qt = 128-query tile index
    if (t == 0) {                         // longest unsplit task first
        qt = 8; k_begin = 0; k_end = 18; pidx = -1;
    } else if (t <= 14) {                 // split tasks, qt = 15..9
        qt = 15 - ((t - 1) >> 1);
        const int half = (t - 1) & 1;
        const int n = 2 * qt + 2, h0 = n >> 1;
        k_begin = half ? h0 : 0;
        k_end   = half ? n  : h0;
        pidx = ((qt - 9) * 32 + bh) * 2 + half;
    } else {                              // unsplit, qt = 7..0
        qt = 22 - t;
        k_begin = 0; k_end = 2 * qt + 2;
        pidx = -1;
    }
    const int kmask0 = 2 * qt;            // first tile needing the causal mask
    const int q0 = qt * 128;
    const int bb = bh >> 4, h = bh & 15;
    short* Pw = &Ps[wave][0];

    // Q fragments: wave owns queries q0 + wave*32 + qs*16 + ln
    short8 qb[2][2];
    int q_abs[2];
    for (int qs = 0; qs < 2; qs++) {
        const int q = q0 + wave * 32 + qs * 16 + ln;
        q_abs[qs] = q;
        const short* qrow = Q + ((size_t)bh * S_LEN + q) * HD;
        qb[qs][0] = *(const short8*)(qrow + quad * 8);
        qb[qs][1] = *(const short8*)(qrow + 32 + quad * 8);
    }

    float l_part[2] = {0.f, 0.f};
    floatx4 o_acc[2][4] = {};

    for (int kt = k_begin; kt < k_end; kt++) {
        const int k0 = kt * 64;
        __syncthreads();
        for (int tt = 0; tt < 2; tt++) {
            const int c = tt * 256 + tid;            // 0..511
            const int row = c >> 3, pos = c & 7, src = pos ^ (row & 7);
            gll16(Kg + ((size_t)bh * S_LEN + k0 + row) * HD + src * 8, Ks + c * 8);
            gll16(Vt + ((size_t)bh * HD + row) * S_LEN + k0 + src * 8, Vs + c * 8);
        }
        __syncthreads();

        for (int qs = 0; qs < 2; qs++) {
            // S^T: D[m=key(nt*16+quad*4+r)][n=query(ln)], 4 tiles over 64 keys
            floatx4 sc[4];
            for (int nt = 0; nt < 4; nt++) {
                const int row = nt * 16 + ln;
                const short8 ak0 = *(const short8*)(Ks + row * 64 + ((quad ^ (ln & 7)) * 8));
                const short8 ak1 = *(const short8*)(Ks + row * 64 + (((4 + quad) ^ (ln & 7)) * 8));
                floatx4 z = {};
                z = __builtin_amdgcn_mfma_f32_16x16x32_bf16(ak0, qb[qs][0], z, 0, 0, 0);
                z = __builtin_amdgcn_mfma_f32_16x16x32_bf16(ak1, qb[qs][1], z, 0, 0, 0);
                sc[nt] = z;
            }

            if (kt >= kmask0) {   // causal mask: key > query
                for (int nt = 0; nt < 4; nt++)
                    for (int r = 0; r < 4; r++)
                        if (k0 + nt * 16 + quad * 4 + r > q_abs[qs]) sc[nt][r] = -1e30f;
            }

            // fixed-base softmax: p = exp2(s); per-lane l only
            float ls = 0.f;
            for (int nt = 0; nt < 4; nt++)
                for (int r = 0; r < 4; r++) {
                    const float e = exp2f(sc[nt][r]);
                    sc[nt][r] = e; ls += e;
                }
            l_part[qs] += ls;

            // P^T -> B-operand layout via wave-private LDS [q=ln][key]
            short* Pq = Pw + qs * 16 * PST2;
            for (int nt = 0; nt < 4; nt++) {
                uint2 u;
                u.x = pack2(sc[nt][0], sc[nt][1]);
                u.y = pack2(sc[nt][2], sc[nt][3]);
                *(uint2*)&Pq[ln * PST2 + nt * 16 + quad * 4] = u;
            }

            // O^T += V^T · P^T : D[m=d][n=q], 64-key K-dim (2 steps)
            for (int ks = 0; ks < 2; ks++) {
                const short8 bp = *(const short8*)&Pq[ln * PST2 + ks * 32 + quad * 8];
                for (int dt = 0; dt < 4; dt++) {
                    const int row = dt * 16 + ln;
                    const short8 av = *(const short8*)(Vs + row * 64 + (((ks * 4 + quad) ^ (ln & 7)) * 8));
                    o_acc[qs][dt] = __builtin_amdgcn_mfma_f32_16x16x32_bf16(av, bp, o_acc[qs][dt], 0, 0, 0);
                }
            }
        }
    }

    // reduce l across the 4 quads once
    float l_tot[2];
    for (int qs = 0; qs < 2; qs++) {
        float l = l_part[qs];
        l += __shfl_xor(l, 16, 64);
        l += __shfl_xor(l, 32, 64);
        l_tot[qs] = l;
    }

    if (pidx >= 0) {
        for (int qs = 0; qs < 2; qs++) {
            const int q = wave * 32 + qs * 16 + ln;
            float* Ob = Opart + (size_t)pidx * 8192 + q * 64;
            for (int dt = 0; dt < 4; dt++)
                *(float4*)(Ob + dt * 16 + quad * 4) = *(float4*)&o_acc[qs][dt];
            if (quad == 0) Lpart[(size_t)pidx * 128 + q] = l_tot[qs];
        }
    } else {
        for (int qs = 0; qs < 2; qs++) {
            const float rl = 1.f / l_tot[qs];
            short* Pq = Pw + qs * 16 * PST2;
            for (int dt = 0; dt < 4; dt++) {
                uint2 u;
                u.x = pack2(o_acc[qs][dt][0] * rl, o_acc[qs][dt][1] * rl);
                u.y = pack2(o_acc[qs][dt][2] * rl, o_acc[qs][dt][3] * rl);
                *(uint2*)&Pq[ln * PST2 + dt * 16 + quad * 4] = u;   // [q=ln][d]
            }
            const int qr = lane >> 2, sg = lane & 3;
            for (int c = 0; c < 2; c++) {
                const short8 v = *(const short8*)&Pq[qr * PST2 + sg * 8 + c * 32];
                const int s = q0 + wave * 32 + qs * 16 + qr;
                *(short8*)(ctx + ((size_t)bb * S_LEN + s) * D_DIM + h * HD + sg * 8 + c * 32) = v;
            }
        }
    }
}

// ---------------- combine split partials -> ctx (shared base, no exp) ----------------
__global__ __launch_bounds__(256) void combine_kernel(const float* __restrict__ Opart,
                                                      const float* __restrict__ Lpart,
                                                      short* __restrict__ ctx) {
    const int tile = blockIdx.x;          // 0..223
    const int qt = 9 + (tile >> 5), bh = tile & 31;
    const int bb = bh >> 4, h = bh & 15;
    const int p0 = ((qt - 9) * 32 + bh) * 2;
    const float* O0 = Opart + (size_t)p0 * 8192;
    const float* O1 = O0 + 8192;
    const float* l0 = Lpart + (size_t)p0 * 128;
    const float* l1 = l0 + 128;
    for (int e = threadIdx.x; e < 2048; e += 256) {   // float4 units
        const int q = e >> 4, seg = e & 15;
        const float rl = 1.f / (l0[q] + l1[q]);
        const float4 x0 = *(const float4*)(O0 + q * 64 + seg * 4);
        const float4 x1 = *(const float4*)(O1 + q * 64 + seg * 4);
        uint2 u;
        u.x = pack2((x0.x + x1.x) * rl, (x0.y + x1.y) * rl);
        u.y = pack2((x0.z + x1.z) * rl, (x0.w + x1.w) * rl);
        const int s = qt * 128 + q;
        *(uint2*)(ctx + ((size_t)bb * S_LEN + s) * D_DIM + h * HD + seg * 4) = u;
    }
}

// ---------------- launch ----------------
extern "C" void kernel_launch(void* const* d_in, const int* in_sizes, int n_in,
                              void* d_out, int out_size, void* d_ws, size_t ws_size,
                              hipStream_t stream) {
    const float* X  = (const float*)d_in[0];
    const float* Wq = (const float*)d_in[1];
    const float* Wk = (const float*)d_in[2];
    const float* Wv = (const float*)d_in[3];
    const float* Wo = (const float*)d_in[4];
    const float* bo = (const float*)d_in[5];
    float* out = (float*)d_out;

    char* ws = (char*)d_ws;
    const size_t MB = 1024 * 1024;
    short* Xb     = (short*)(ws);                 //  0- 8 MB (dead after QKV GEMM)
    short* WqkvT  = (short*)(ws + 8  * MB);       //  8-14 MB (dead after QKV GEMM)
    short* Qb     = (short*)(ws + 16 * MB);       // 16-24 MB [B,H,S,HD], pre-scaled by log2e
    short* Kb     = (short*)(ws + 24 * MB);       // 24-32 MB [B,H,S,HD]
    short* Vtb    = (short*)(ws + 32 * MB);       // 32-40 MB [B,H,HD,S]
    short* ctxb   = (short*)(ws + 40 * MB);       // 40-48 MB [4096][1024]
    short* WoT    = (short*)(ws + 48 * MB);       // 48-50 MB
    float* Opart  = (float*)(ws);                 //  0-14.7 MB, reuses dead region
    float* Lpart  = (float*)(ws + 50 * MB);       // 50-50.22 MB

    prep_kernel<<<8192, 256, 0, stream>>>(X, Wq, Wk, Wv, Wo, Xb, WqkvT, WoT);

    dim3 gq(32, 24);   // M=4096/128, N=3072/128
    gemm_qkv_kernel<<<gq, 512, 0, stream>>>(Xb, WqkvT, Qb, Kb, Vtb);

    attn_kernel<<<736, 256, 0, stream>>>(Qb, Kb, Vtb, ctxb, Opart, Lpart);
    combine_kernel<<<224, 256, 0, stream>>>(Opart, Lpart, ctxb);

    dim3 go(32, 16);   // M=4096/128, N=1024/64 -> 512 blocks
    gemm_out_kernel<<<go, 512, 0, stream>>>(ctxb, WoT, out, bo);
}

// Round 13
// 186.290 us; speedup vs baseline: 1.0972x; 1.0972x over previous
//
#include <hip/hip_runtime.h>
#include <stdint.h>

// B=2, S=2048, D=1024, H=16, HD=64. fp32 in/out, bf16 MFMA internally.

typedef __attribute__((ext_vector_type(8))) short short8;
typedef __attribute__((ext_vector_type(4))) float floatx4;
typedef __attribute__((ext_vector_type(16))) float floatx16;

#define S_LEN 2048
#define D_DIM 1024
#define NH 16
#define HD 64
#define L2E 1.44269504088896340736f

__device__ __forceinline__ short f2bf(float f) {
    uint32_t u = __builtin_bit_cast(uint32_t, f);
    uint32_t r = u + 0x7fffu + ((u >> 16) & 1u);   // RNE
    return (short)(r >> 16);
}
__device__ __forceinline__ uint32_t pack2(float a, float b) {
#if __has_builtin(__builtin_amdgcn_cvt_pk_bf16_f32)
    auto v = __builtin_amdgcn_cvt_pk_bf16_f32(a, b);
    uint32_t r; __builtin_memcpy(&r, &v, sizeof(r)); return r;
#else
    return (uint32_t)(uint16_t)f2bf(a) | ((uint32_t)(uint16_t)f2bf(b) << 16);
#endif
}
__device__ __forceinline__ void gll16(const void* g, void* l) {
    __builtin_amdgcn_global_load_lds(
        (const __attribute__((address_space(1))) void*)g,
        (__attribute__((address_space(3))) void*)l, 16, 0, 0);
}

// ---------------- prep: cast X + transpose-cast 4 weights, one launch ----------------
__global__ __launch_bounds__(256) void prep_kernel(const float* __restrict__ X,
                                                   const float* __restrict__ Wq,
                                                   const float* __restrict__ Wk,
                                                   const float* __restrict__ Wv,
                                                   const float* __restrict__ Wo,
                                                   short* __restrict__ Xb,
                                                   short* __restrict__ WqkvT,
                                                   short* __restrict__ WoT) {
    __shared__ float tile[32][33];
    const int id = blockIdx.x, tid = threadIdx.x;
    if (id < 4096) {                                  // castx: one float4/thread
        const int i = id * 256 + tid;
        const float4 v = *(const float4*)(X + (size_t)i * 4);
        uint2 o;
        o.x = pack2(v.x, v.y);
        o.y = pack2(v.z, v.w);
        *(uint2*)(Xb + (size_t)i * 4) = o;
    } else {                                          // tcast: 32x32 tile
        const int f = id - 4096;                      // 0..4095
        const int z = f >> 10, r = f & 1023;
        const float* W = (z == 0) ? Wq : (z == 1) ? Wk : (z == 2) ? Wv : Wo;
        short* WT = (z < 3) ? (WqkvT + (size_t)z * 1024 * 1024) : WoT;
        const int bx = (r & 31) * 32, by = (r >> 5) * 32;
        const int tx = tid & 31, ty = tid >> 5;       // 32 x 8
        for (int i = 0; i < 32; i += 8)
            tile[ty + i][tx] = W[(size_t)(bx + ty + i) * D_DIM + by + tx];
        __syncthreads();
        for (int i = 0; i < 32; i += 8)
            WT[(size_t)(by + ty + i) * D_DIM + bx + tx] = f2bf(tile[tx][ty + i]);
    }
}

// ---------------- GEMM mainloop: 128x128 tile, BK=64, 8 waves ----------------
__device__ __forceinline__ void gemm_main8(const short* __restrict__ A,
                                           const short* __restrict__ BT,
                                           short* As, short* Bs,
                                           int m0, int n0, floatx4 (&acc)[4][2],
                                           int tid) {
    const int lane = tid & 63, ln = lane & 15, quad = lane >> 4;
    const int wave = tid >> 6;
    const int mw = (wave & 1) * 64, nw = (wave >> 1) * 32;
    for (int k0 = 0; k0 < D_DIM; k0 += 64) {
        __syncthreads();
        for (int t = 0; t < 2; t++) {
            const int c = t * 512 + tid;             // 0..1023
            const int row = c >> 3, pos = c & 7, src = pos ^ (row & 7);
            gll16(A  + (size_t)(m0 + row) * D_DIM + k0 + src * 8, As + c * 8);
            gll16(BT + (size_t)(n0 + row) * D_DIM + k0 + src * 8, Bs + c * 8);
        }
        __syncthreads();
        for (int ks = 0; ks < 2; ks++) {
            short8 a[4], b[2];
            for (int i = 0; i < 4; i++) {
                const int row = mw + i * 16 + ln;
                a[i] = *(const short8*)(As + row * 64 + (((ks * 4 + quad) ^ (ln & 7)) * 8));
            }
            for (int j = 0; j < 2; j++) {
                const int row = nw + j * 16 + ln;
                b[j] = *(const short8*)(Bs + row * 64 + (((ks * 4 + quad) ^ (ln & 7)) * 8));
            }
            for (int i = 0; i < 4; i++)
                for (int j = 0; j < 2; j++)
                    acc[i][j] = __builtin_amdgcn_mfma_f32_16x16x32_bf16(a[i], b[j], acc[i][j], 0, 0, 0);
        }
    }
}

// fused QKV: grid (32, 24), 512 threads. Q pre-scaled by log2(e).
__global__ __launch_bounds__(512) void gemm_qkv_kernel(const short* __restrict__ Xb,
                                                       const short* __restrict__ WT,
                                                       short* __restrict__ Qb,
                                                       short* __restrict__ Kb,
                                                       short* __restrict__ Vtb) {
    __shared__ __align__(16) short As[128 * 64];
    __shared__ __align__(16) short Bs[128 * 64];
    const int m0 = blockIdx.x * 128, n0 = blockIdx.y * 128;
    floatx4 acc[4][2] = {};
    gemm_main8(Xb, WT, As, Bs, m0, n0, acc, threadIdx.x);

    const int tid = threadIdx.x, wave = tid >> 6, lane = tid & 63;
    const int ln = lane & 15, quad = lane >> 4;
    const int mw = (wave & 1) * 64, nw = (wave >> 1) * 32;
    const int nsel = n0 >> 10;              // 0:Q 1:K 2:V
    const float qs = (nsel == 0) ? L2E : 1.f;
    short* outB = (nsel == 0) ? Qb : (nsel == 1 ? Kb : Vtb);
    for (int i = 0; i < 4; i++)
        for (int j = 0; j < 2; j++)
            for (int r = 0; r < 4; r++) {
                const int row = m0 + mw + i * 16 + quad * 4 + r;   // token
                const int col = (n0 & 1023) + nw + j * 16 + ln;    // feature
                const int bb = row >> 11, s = row & (S_LEN - 1);
                const int h = col >> 6, hd = col & (HD - 1);
                const short v = f2bf(acc[i][j][r] * qs);
                if (nsel < 2)
                    outB[(((size_t)(bb * NH + h)) * S_LEN + s) * HD + hd] = v;
                else
                    outB[(((size_t)(bb * NH + h)) * HD + hd) * S_LEN + s] = v;
            }
}

// ---------------- output projection: BM=128 x BN=64, grid (32,16) ----------------
__global__ __launch_bounds__(512) void gemm_out_kernel(const short* __restrict__ Cb,
                                                       const short* __restrict__ WoT,
                                                       float* __restrict__ out,
                                                       const float* __restrict__ bias) {
    __shared__ __align__(16) short As[128 * 64];   // 16 KB
    __shared__ __align__(16) short Bs[64 * 64];    // 8 KB
    const int m0 = blockIdx.x * 128, n0 = blockIdx.y * 64;
    const int tid = threadIdx.x, lane = tid & 63;
    const int ln = lane & 15, quad = lane >> 4;
    const int wave = tid >> 6;
    const int mw = (wave & 3) * 32, nw = (wave >> 2) * 32;

    floatx4 acc[2][2] = {};

    for (int k0 = 0; k0 < D_DIM; k0 += 64) {
        __syncthreads();
        for (int t = 0; t < 2; t++) {            // A: 1024 chunks
            const int c = t * 512 + tid;
            const int row = c >> 3, pos = c & 7, src = pos ^ (row & 7);
            gll16(Cb + (size_t)(m0 + row) * D_DIM + k0 + src * 8, As + c * 8);
        }
        {                                        // B: 512 chunks
            const int c = tid;
            const int row = c >> 3, pos = c & 7, src = pos ^ (row & 7);
            gll16(WoT + (size_t)(n0 + row) * D_DIM + k0 + src * 8, Bs + c * 8);
        }
        __syncthreads();
        for (int ks = 0; ks < 2; ks++) {
            short8 a[2], b[2];
            for (int i = 0; i < 2; i++) {
                const int row = mw + i * 16 + ln;
                a[i] = *(const short8*)(As + row * 64 + (((ks * 4 + quad) ^ (ln & 7)) * 8));
            }
            for (int j = 0; j < 2; j++) {
                const int row = nw + j * 16 + ln;
                b[j] = *(const short8*)(Bs + row * 64 + (((ks * 4 + quad) ^ (ln & 7)) * 8));
            }
            for (int i = 0; i < 2; i++)
                for (int j = 0; j < 2; j++)
                    acc[i][j] = __builtin_amdgcn_mfma_f32_16x16x32_bf16(a[i], b[j], acc[i][j], 0, 0, 0);
        }
    }

    for (int i = 0; i < 2; i++)
        for (int j = 0; j < 2; j++)
            for (int r = 0; r < 4; r++) {
                const int row = m0 + mw + i * 16 + quad * 4 + r;
                const int col = n0 + nw + j * 16 + ln;
                out[(size_t)row * D_DIM + col] = acc[i][j][r] + bias[col];
            }
}

// ---------------- causal flash attention: R8 grid, 32x32x16 MFMA ----------------
// 1536 blocks, 64 queries/block, 128-key staging tiles, qt>=16 split, XCD head
// affinity, fixed-base softmax (Q pre-scaled by log2e).
// Waves: qsel=wave&1 picks query half (32 q), ksel=wave>>1 picks key half (64 k)
// of each 128-key tile. Each wave: S^T(64k x 32q) via 2x4 mfma_32x32x16, PV via
// 2x4. Halves per-iter LDS fragment traffic vs the 16x16 form. One cross-wave
// O/l merge (ksel pairs) through LDS at block end.
// 32x32 C/D layout [m74/m101]: col=lane&31, row=(reg&3)+8*(reg>>2)+4*(lane>>5).
__global__ __launch_bounds__(256) void attn_kernel(const short* __restrict__ Q,
                                                   const short* __restrict__ Kg,
                                                   const short* __restrict__ Vt,
                                                   short* __restrict__ ctx,
                                                   float* __restrict__ Opart,
                                                   float* __restrict__ Lpart) {
    __shared__ __align__(16) short SMEM[24704];   // 49408 B
    short* Ks = SMEM;                 // [128 key][64 hd]   8192 shorts
    short* Vs = SMEM + 8192;          // [64 hd][128 key]   8192 shorts
    short* Ps = SMEM + 16384;         // 4 waves x [32 q][64] 8192 shorts
    float* Lpool = (float*)(SMEM + 24576);  // 64 floats
    float* Opool = (float*)SMEM;      // end-of-block merge: 2 x [32 q][68] floats

    const int tid = threadIdx.x, wave = tid >> 6, lane = tid & 63;
    const int lq = lane & 31, lh = lane >> 5;
    const int qsel = wave & 1, ksel = wave >> 1;

    const int id = blockIdx.x;            // 0..1535
    const int bh = (id & 7) + 8 * ((id >> 3) & 3);
    const int t = id >> 5;                // 0..47
    int qt, k_begin, k_end, pidx;
    if (t < 32) {                         // split tasks, qt = 31..16
        qt = 31 - (t >> 1);
        const int half = t & 1;
        const int n = (qt + 2) >> 1;      // 128-key tiles
        const int h0 = n >> 1;
        k_begin = half ? h0 : 0;
        k_end   = half ? n  : h0;
        pidx = ((qt - 16) * 32 + bh) * 2 + half;
    } else {                              // unsplit, qt = 15..0
        qt = 47 - t;
        k_begin = 0; k_end = (qt + 2) >> 1;
        pidx = -1;
    }
    const int kmask = ((qt + 2) >> 1) - 1;
    const int q0 = qt * 64;
    const int bb = bh >> 4, h = bh & 15;
    const int kbase = ksel * 64;
    short* Pq = Ps + wave * 2048;         // this wave's [32 q][64] region

    // Q fragments (B-operand): B[n=lq][k=t*16 + lh*8 + j]
    const int q_abs = q0 + qsel * 32 + lq;
    const short* qrow = Q + ((size_t)bh * S_LEN + q_abs) * HD;
    short8 qb[4];
    for (int tt = 0; tt < 4; tt++)
        qb[tt] = *(const short8*)(qrow + tt * 16 + lh * 8);

    float l_part = 0.f;
    floatx16 o_acc[2] = {};

    for (int kt = k_begin; kt < k_end; kt++) {
        const int k0 = kt * 128;
        __syncthreads();
        for (int tt = 0; tt < 4; tt++) {
            const int c = tt * 256 + tid;
            {   // K tile: 128 rows x 64 hd
                const int row = c >> 3, pos = c & 7, src = pos ^ (row & 7);
                gll16(Kg + ((size_t)bh * S_LEN + k0 + row) * HD + src * 8, Ks + c * 8);
            }
            {   // V^T tile: 64 rows x 128 keys
                const int row = c >> 4, pos = c & 15, src = pos ^ (row & 15);
                gll16(Vt + ((size_t)bh * HD + row) * S_LEN + k0 + src * 8, Vs + c * 8);
            }
        }
        __syncthreads();

        // S^T: two 32-key subtiles x 32 queries, K-dim = 64 hd (4 mfma each)
        floatx16 sc[2];
        for (int m = 0; m < 2; m++) {
            const int row = kbase + m * 32 + lq;      // key row; row&7 == lq&7
            floatx16 z = {};
            for (int tt = 0; tt < 4; tt++) {
                const short8 ak = *(const short8*)(Ks + row * 64 + (((tt * 2 + lh) ^ (lq & 7)) * 8));
                z = __builtin_amdgcn_mfma_f32_32x32x16_bf16(ak, qb[tt], z, 0, 0, 0);
            }
            sc[m] = z;
        }

        if (kt == kmask) {  // diagonal tile: mask key > query
            for (int m = 0; m < 2; m++)
                for (int reg = 0; reg < 16; reg++) {
                    const int kglob = k0 + kbase + m * 32 + (reg & 3) + 8 * (reg >> 2) + 4 * lh;
                    if (kglob > q_abs) sc[m][reg] = -1e30f;
                }
        }

        // fixed-base softmax: p = exp2(s); per-lane l only
        float ls = 0.f;
        for (int m = 0; m < 2; m++)
            for (int reg = 0; reg < 16; reg++) {
                const float e = exp2f(sc[m][reg]);
                sc[m][reg] = e; ls += e;
            }
        l_part += ls;

        // P^T -> B-operand via wave-private LDS [q=lq][key 64], seg-xor swizzled
        for (int m = 0; m < 2; m++)
            for (int rg = 0; rg < 4; rg++) {
                uint2 u;
                u.x = pack2(sc[m][rg * 4 + 0], sc[m][rg * 4 + 1]);
                u.y = pack2(sc[m][rg * 4 + 2], sc[m][rg * 4 + 3]);
                *(uint2*)&Pq[lq * 64 + (((m * 4 + rg) ^ (lq & 7)) * 8) + 4 * lh] = u;
            }
        short8 bp[4];
        for (int g = 0; g < 4; g++)
            bp[g] = *(const short8*)&Pq[lq * 64 + (((g * 2 + lh) ^ (lq & 7)) * 8)];

        // O^T += V^T . P^T : two 32-d subtiles, K-dim = wave's 64 keys
        for (int dt = 0; dt < 2; dt++) {
            const int row = dt * 32 + lq;             // d row; row&15 == lq&15
            for (int g = 0; g < 4; g++) {
                const int seg = (kbase >> 3) + g * 2 + lh;
                const short8 av = *(const short8*)(Vs + row * 128 + ((seg ^ (lq & 15)) * 8));
                o_acc[dt] = __builtin_amdgcn_mfma_f32_32x32x16_bf16(av, bp[g], o_acc[dt], 0, 0, 0);
            }
        }
    }

    // lane-half l reduce (lanes q, q+32 hold same query's different keys)
    l_part += __shfl_xor(l_part, 32, 64);

    // cross-wave merge: ksel=1 exports to LDS, ksel=0 accumulates + finalizes
    __syncthreads();
    if (ksel == 1) {
        float* Op = Opool + qsel * 32 * 68;
        for (int dt = 0; dt < 2; dt++)
            for (int rg = 0; rg < 4; rg++) {
                float4 v;
                v.x = o_acc[dt][rg * 4 + 0]; v.y = o_acc[dt][rg * 4 + 1];
                v.z = o_acc[dt][rg * 4 + 2]; v.w = o_acc[dt][rg * 4 + 3];
                *(float4*)&Op[lq * 68 + dt * 32 + 8 * rg + 4 * lh] = v;
            }
        if (lane < 32) Lpool[qsel * 32 + lq] = l_part;
    }
    __syncthreads();
    if (ksel == 0) {
        const float* Op = Opool + qsel * 32 * 68;
        float om[2][16];
        for (int dt = 0; dt < 2; dt++)
            for (int rg = 0; rg < 4; rg++) {
                const float4 v = *(const float4*)&Op[lq * 68 + dt * 32 + 8 * rg + 4 * lh];
                om[dt][rg * 4 + 0] = o_acc[dt][rg * 4 + 0] + v.x;
                om[dt][rg * 4 + 1] = o_acc[dt][rg * 4 + 1] + v.y;
                om[dt][rg * 4 + 2] = o_acc[dt][rg * 4 + 2] + v.z;
                om[dt][rg * 4 + 3] = o_acc[dt][rg * 4 + 3] + v.w;
            }
        const float l_tot = l_part + Lpool[qsel * 32 + lq];

        if (pidx >= 0) {
            // unnormalized fp32 partials [q 64][d 64]
            float* Ob = Opart + (size_t)pidx * 4096 + (qsel * 32 + lq) * 64;
            for (int dt = 0; dt < 2; dt++)
                for (int rg = 0; rg < 4; rg++) {
                    float4 v;
                    v.x = om[dt][rg * 4 + 0]; v.y = om[dt][rg * 4 + 1];
                    v.z = om[dt][rg * 4 + 2]; v.w = om[dt][rg * 4 + 3];
                    *(float4*)(Ob + dt * 32 + 8 * rg + 4 * lh) = v;
                }
            if (lane < 32) Lpart[(size_t)pidx * 64 + qsel * 32 + lq] = l_tot;
        } else {
            // normalize, stage bf16 [q][d] in own Ps region, coalesced stores
            const float rl = 1.f / l_tot;
            for (int dt = 0; dt < 2; dt++)
                for (int rg = 0; rg < 4; rg++) {
                    uint2 u;
                    u.x = pack2(om[dt][rg * 4 + 0] * rl, om[dt][rg * 4 + 1] * rl);
                    u.y = pack2(om[dt][rg * 4 + 2] * rl, om[dt][rg * 4 + 3] * rl);
                    *(uint2*)&Pq[lq * 64 + (((dt * 4 + rg) ^ (lq & 7)) * 8) + 4 * lh] = u;
                }
            const int qr = lane >> 1, sg = lane & 1;
            for (int c = 0; c < 4; c++) {
                const short8 v = *(const short8*)&Pq[qr * 64 + (((c * 2 + sg) ^ (qr & 7)) * 8)];
                const int s = q0 + qsel * 32 + qr;
                *(short8*)(ctx + ((size_t)bb * S_LEN + s) * D_DIM + h * HD + c * 16 + sg * 8) = v;
            }
        }
    }
}

// ---------------- combine split partials -> ctx (shared base, no exp) ----------------
__global__ __launch_bounds__(256) void combine_kernel(const float* __restrict__ Opart,
                                                      const float* __restrict__ Lpart,
                                                      short* __restrict__ ctx) {
    const int tile = blockIdx.x;          // 0..511
    const int qt = 16 + (tile >> 5), bh = tile & 31;
    const int bb = bh >> 4, h = bh & 15;
    const int p0 = ((qt - 16) * 32 + bh) * 2;
    const float* O0 = Opart + (size_t)p0 * 4096;
    const float* O1 = O0 + 4096;
    const float* l0 = Lpart + (size_t)p0 * 64;
    const float* l1 = l0 + 64;
    for (int e = threadIdx.x; e < 1024; e += 256) {   // float4 units
        const int q = e >> 4, seg = e & 15;
        const float rl = 1.f / (l0[q] + l1[q]);
        const float4 x0 = *(const float4*)(O0 + q * 64 + seg * 4);
        const float4 x1 = *(const float4*)(O1 + q * 64 + seg * 4);
        uint2 u;
        u.x = pack2((x0.x + x1.x) * rl, (x0.y + x1.y) * rl);
        u.y = pack2((x0.z + x1.z) * rl, (x0.w + x1.w) * rl);
        const int s = qt * 64 + q;
        *(uint2*)(ctx + ((size_t)bb * S_LEN + s) * D_DIM + h * HD + seg * 4) = u;
    }
}

// ---------------- launch ----------------
extern "C" void kernel_launch(void* const* d_in, const int* in_sizes, int n_in,
                              void* d_out, int out_size, void* d_ws, size_t ws_size,
                              hipStream_t stream) {
    const float* X  = (const float*)d_in[0];
    const float* Wq = (const float*)d_in[1];
    const float* Wk = (const float*)d_in[2];
    const float* Wv = (const float*)d_in[3];
    const float* Wo = (const float*)d_in[4];
    const float* bo = (const float*)d_in[5];
    float* out = (float*)d_out;

    char* ws = (char*)d_ws;
    const size_t MB = 1024 * 1024;
    short* Xb     = (short*)(ws);                 //  0- 8 MB (dead after QKV GEMM)
    short* WqkvT  = (short*)(ws + 8  * MB);       //  8-14 MB (dead after QKV GEMM)
    short* Qb     = (short*)(ws + 16 * MB);       // 16-24 MB [B,H,S,HD], pre-scaled by log2e
    short* Kb     = (short*)(ws + 24 * MB);       // 24-32 MB [B,H,S,HD]
    short* Vtb    = (short*)(ws + 32 * MB);       // 32-40 MB [B,H,HD,S]
    short* ctxb   = (short*)(ws + 40 * MB);       // 40-48 MB [4096][1024]
    short* WoT    = (short*)(ws + 48 * MB);       // 48-50 MB
    float* Opart  = (float*)(ws);                 //  0-16 MB (1024 tasks x 16 KB, exact)
    float* Lpart  = (float*)(ws + 50 * MB);       // 50-50.25 MB

    prep_kernel<<<8192, 256, 0, stream>>>(X, Wq, Wk, Wv, Wo, Xb, WqkvT, WoT);

    dim3 gq(32, 24);   // M=4096/128, N=3072/128
    gemm_qkv_kernel<<<gq, 512, 0, stream>>>(Xb, WqkvT, Qb, Kb, Vtb);

    attn_kernel<<<1536, 256, 0, stream>>>(Qb, Kb, Vtb, ctxb, Opart, Lpart);
    combine_kernel<<<512, 256, 0, stream>>>(Opart, Lpart, ctxb);

    dim3 go(32, 16);   // M=4096/128, N=1024/64 -> 512 blocks
    gemm_out_kernel<<<go, 512, 0, stream>>>(ctxb, WoT, out, bo);
}